// Round 5
// baseline (141.871 us; speedup 1.0000x reference)
//
#include <hip/hip_runtime.h>
#include <hip/hip_bf16.h>

#define NUM_ENT 50000
#define NUM_REL 500
#define DIM 128
#define BQ 1024
#define KN 32
#define TBL 729          // dt in [-364, 364]
#define NTILE 256        // entities per score block
#define NXT 196          // 196*256 = 50176 >= 50000; max row 50175 < 50501 in-bounds

typedef _Float16 f16x8 __attribute__((ext_vector_type(8)));
typedef float f32x4 __attribute__((ext_vector_type(4)));

// ---------------- Kernel A: fold weights + cos table (fused; proven r3) --------
__global__ void prep_kernel(const float* __restrict__ gcn_w_w,
                            const float* __restrict__ gcn_w_b,
                            const float* __restrict__ proj_w,
                            const float* __restrict__ proj_b,
                            const float* __restrict__ phase,
                            const float* __restrict__ basis_freq,
                            float* __restrict__ W,
                            float* __restrict__ bias,
                            float* __restrict__ Call,
                            float* __restrict__ COS) {
    int j = blockIdx.x;
    int d = threadIdx.x;
    if (j < 256) {
        float acc = 0.f;
        for (int f = 0; f < DIM; ++f)
            acc += gcn_w_w[d * 256 + f] * proj_w[f * 256 + j];
        W[j * DIM + d] = acc;
    } else if (j < 384) {
        W[j * DIM + d] = gcn_w_w[d * 256 + 128 + (j - 256)];
    } else if (j == 384) {
        float b1 = 0.f;
        for (int f = 0; f < DIM; ++f) b1 += proj_b[f] * gcn_w_w[d * 256 + f];
        bias[d] = b1 + gcn_w_b[d];
        float cc = 0.f;
        for (int g = 0; g < DIM; ++g) cc += cosf(phase[g]) * proj_w[d * 256 + 128 + g];
        Call[d] = cc + proj_b[d];
    } else {
        int row = j - 385;                 // 0..728
        COS[row * DIM + d] = cosf((float)(row - 364) * basis_freq[d] + phase[d]);
    }
}

// ---------------- Kernel C: per-query pipeline (verbatim rounds 1-2, proven) ----
__global__ void query_kernel(const int* __restrict__ rel_idx,
                             const int* __restrict__ ts,
                             const int* __restrict__ ngh_node,
                             const int* __restrict__ ngh_eidx,
                             const int* __restrict__ ngh_ts,
                             const float* __restrict__ symbol_emb,
                             const float* __restrict__ proj_w,
                             const float* __restrict__ W,
                             const float* __restrict__ bias,
                             const float* __restrict__ Call,
                             const float* __restrict__ COS,
                             float* __restrict__ cOut,
                             _Float16* __restrict__ uOut) {
    int b = blockIdx.x;
    int t = threadIdx.x;   // 0..127
    __shared__ int sE[KN], sR[KN], sT[KN];
    __shared__ float sAgg[3][DIM];
    __shared__ float sQ[DIM];
    __shared__ float sRed[DIM];

    if (t < KN) {
        sE[t] = ngh_node[b * KN + t];
        sR[t] = ngh_eidx[b * KN + t];
        sT[t] = ngh_ts[b * KN + t] - ts[b] + 364;
    }
    __syncthreads();

    float aN = 0.f, aC = 0.f, aR = 0.f;
    int cnt = 0;
    for (int k = 0; k < KN; ++k) {
        int e = sE[k];
        if (e < 0) continue;
        cnt++;
        aN += symbol_emb[(size_t)e * DIM + t];
        aC += COS[sT[k] * DIM + t];
        aR += symbol_emb[(size_t)(NUM_ENT + sR[k]) * DIM + t];
    }
    sAgg[0][t] = aN; sAgg[1][t] = aC; sAgg[2][t] = aR;
    __syncthreads();

    float acc = (float)cnt * bias[t];
    #pragma unroll 8
    for (int j = 0; j < DIM; ++j) acc += sAgg[0][j] * W[j * DIM + t];
    #pragma unroll 8
    for (int j = 0; j < DIM; ++j) acc += sAgg[1][j] * W[(128 + j) * DIM + t];
    #pragma unroll 8
    for (int j = 0; j < DIM; ++j) acc += sAgg[2][j] * W[(256 + j) * DIM + t];

    float denom = (float)(cnt > 0 ? cnt : 1);
    float sub = tanhf(acc / denom);
    float q = sub * symbol_emb[(size_t)(NUM_ENT + rel_idx[b]) * DIM + t];
    sQ[t] = q;
    __syncthreads();

    float u = 0.f;
    #pragma unroll 8
    for (int dd = 0; dd < DIM; ++dd) u += sQ[dd] * proj_w[dd * 256 + t];
    uOut[b * DIM + t] = (_Float16)u;

    sRed[t] = q * Call[t];
    __syncthreads();
    for (int s = 64; s > 0; s >>= 1) {
        if (t < s) sRed[t] += sRed[t + s];
        __syncthreads();
    }
    if (t == 0) cOut[b] = sRed[0];
}

// ---------------- Kernel D: score^T = S-tile(regs) x U ----------------
// Block owns a 256-entity tile: each of 4 waves pins 64 entity rows as f16
// fragments loaded DIRECTLY from symbol_emb f32 (round-3-proven load path),
// then loops over 64 queries. Block writes 1KB contiguous per output row
// (vs 256B in r3) -> fewer partial-128B-line write-allocate fetches; the
// 16 q-chunk blocks of a tile and adjacent tiles are co-XCD for L2 reuse.
__global__ __launch_bounds__(256) void score_kernel(const _Float16* __restrict__ U,
                                                    const float* __restrict__ S,
                                                    const float* __restrict__ cArr,
                                                    float* __restrict__ out) {
    int wgid = blockIdx.x;
    int swz = (wgid & 7) * 392 + (wgid >> 3);   // bijective, 3136 = 8*392
    int xtile = swz >> 4;          // 0..195
    int qchunk = swz & 15;         // 0..15
    int n0 = xtile * NTILE;

    int lane = threadIdx.x & 63;
    int wave = threadIdx.x >> 6;
    int lr = lane & 15;
    int lg = lane >> 4;            // 0..3
    int lk = lg * 8;               // k offset within 32

    // wave pins rows [n0 + wave*64, +64): 16 x f16x8 fragments (f32->f16)
    f16x8 a[4][4];
    #pragma unroll
    for (int nn = 0; nn < 4; ++nn) {
        const float* sp = S + (size_t)(n0 + wave * 64 + nn * 16 + lr) * DIM + lk;
        #pragma unroll
        for (int kk = 0; kk < 4; ++kk) {
            float4 v0 = *reinterpret_cast<const float4*>(sp + kk * 32);
            float4 v1 = *reinterpret_cast<const float4*>(sp + kk * 32 + 4);
            f16x8 af;
            af[0] = (_Float16)v0.x; af[1] = (_Float16)v0.y;
            af[2] = (_Float16)v0.z; af[3] = (_Float16)v0.w;
            af[4] = (_Float16)v1.x; af[5] = (_Float16)v1.y;
            af[6] = (_Float16)v1.z; af[7] = (_Float16)v1.w;
            a[nn][kk] = af;
        }
    }

    int qbase = qchunk * 64;
    #pragma unroll
    for (int qg = 0; qg < 4; ++qg) {
        int q0 = qbase + qg * 16;
        f16x8 bfr[4];
        #pragma unroll
        for (int kk = 0; kk < 4; ++kk)
            bfr[kk] = *reinterpret_cast<const f16x8*>(U + (q0 + lr) * DIM + kk * 32 + lk);
        float cv = cArr[q0 + lr];

        f32x4 acc[4];
        #pragma unroll
        for (int nn = 0; nn < 4; ++nn) acc[nn] = (f32x4){0.f, 0.f, 0.f, 0.f};

        #pragma unroll
        for (int kk = 0; kk < 4; ++kk)
            #pragma unroll
            for (int nn = 0; nn < 4; ++nn)
                acc[nn] = __builtin_amdgcn_mfma_f32_16x16x32_f16(a[nn][kk], bfr[kk], acc[nn], 0, 0, 0);

        int q = q0 + lr;
        #pragma unroll
        for (int nn = 0; nn < 4; ++nn) {
            int e = n0 + wave * 64 + nn * 16 + lg * 4;
            if (e < NUM_ENT) {
                float4 v;
                v.x = acc[nn][0] + cv;
                v.y = acc[nn][1] + cv;
                v.z = acc[nn][2] + cv;
                v.w = acc[nn][3] + cv;
                *reinterpret_cast<float4*>(out + (size_t)q * NUM_ENT + e) = v;
            }
        }
    }
}

extern "C" void kernel_launch(void* const* d_in, const int* in_sizes, int n_in,
                              void* d_out, int out_size, void* d_ws, size_t ws_size,
                              hipStream_t stream) {
    const int*   rel_idx    = (const int*)d_in[1];
    const int*   ts         = (const int*)d_in[2];
    const int*   ngh_node   = (const int*)d_in[3];
    const int*   ngh_eidx   = (const int*)d_in[4];
    const int*   ngh_ts     = (const int*)d_in[5];
    const float* symbol_emb = (const float*)d_in[6];
    const float* gcn_w_w    = (const float*)d_in[7];
    const float* gcn_w_b    = (const float*)d_in[8];
    const float* proj_w     = (const float*)d_in[9];
    const float* proj_b     = (const float*)d_in[10];
    const float* basis_freq = (const float*)d_in[11];
    const float* phase      = (const float*)d_in[12];
    float* out = (float*)d_out;

    char* ws = (char*)d_ws;
    float*     W    = (float*)(ws + 0);          // 384*128*4 = 196608
    float*     bias = (float*)(ws + 196608);     // 512
    float*     Call = (float*)(ws + 197120);     // 512
    float*     COS  = (float*)(ws + 197632);     // 729*128*4 = 373248
    float*     cArr = (float*)(ws + 570880);     // 1024*4 = 4096
    _Float16*  U    = (_Float16*)(ws + 574976);  // 1024*128*2 = 262144

    prep_kernel<<<385 + TBL, 128, 0, stream>>>(gcn_w_w, gcn_w_b, proj_w, proj_b,
                                               phase, basis_freq, W, bias, Call, COS);
    query_kernel<<<BQ, 128, 0, stream>>>(rel_idx, ts, ngh_node, ngh_eidx, ngh_ts,
                                         symbol_emb, proj_w, W, bias, Call, COS,
                                         cArr, U);
    score_kernel<<<NXT * 16, 256, 0, stream>>>(U, symbol_emb, cArr, out);
}

// Round 6
// 129.305 us; speedup vs baseline: 1.0972x; 1.0972x over previous
//
#include <hip/hip_runtime.h>
#include <hip/hip_bf16.h>

#define NUM_ENT 50000
#define NUM_REL 500
#define DIM 128
#define BQ 1024
#define KN 32
#define TBL 729          // dt in [-364, 364]
#define NTILE 256        // entities per score block
#define NXT 196          // 196*256 = 50176 >= 50000; max row 50175 < 50501 in-bounds
#define LDSW 264         // padded words per q-row in LDS transpose buffer

typedef _Float16 f16x8 __attribute__((ext_vector_type(8)));
typedef float f32x4 __attribute__((ext_vector_type(4)));

// ---------------- Kernel A: fold weights + cos table (verbatim r3, proven) -----
__global__ void prep_kernel(const float* __restrict__ gcn_w_w,
                            const float* __restrict__ gcn_w_b,
                            const float* __restrict__ proj_w,
                            const float* __restrict__ proj_b,
                            const float* __restrict__ phase,
                            const float* __restrict__ basis_freq,
                            float* __restrict__ W,
                            float* __restrict__ bias,
                            float* __restrict__ Call,
                            float* __restrict__ COS) {
    int j = blockIdx.x;
    int d = threadIdx.x;
    if (j < 256) {
        float acc = 0.f;
        for (int f = 0; f < DIM; ++f)
            acc += gcn_w_w[d * 256 + f] * proj_w[f * 256 + j];
        W[j * DIM + d] = acc;
    } else if (j < 384) {
        W[j * DIM + d] = gcn_w_w[d * 256 + 128 + (j - 256)];
    } else if (j == 384) {
        float b1 = 0.f;
        for (int f = 0; f < DIM; ++f) b1 += proj_b[f] * gcn_w_w[d * 256 + f];
        bias[d] = b1 + gcn_w_b[d];
        float cc = 0.f;
        for (int g = 0; g < DIM; ++g) cc += cosf(phase[g]) * proj_w[d * 256 + 128 + g];
        Call[d] = cc + proj_b[d];
    } else {
        int row = j - 385;                 // 0..728
        COS[row * DIM + d] = cosf((float)(row - 364) * basis_freq[d] + phase[d]);
    }
}

// ---------------- Kernel C: per-query pipeline (verbatim r3, proven) -----------
__global__ __launch_bounds__(256) void query_kernel(const int* __restrict__ rel_idx,
                             const int* __restrict__ ts,
                             const int* __restrict__ ngh_node,
                             const int* __restrict__ ngh_eidx,
                             const int* __restrict__ ngh_ts,
                             const float* __restrict__ symbol_emb,
                             const float* __restrict__ proj_w,
                             const float* __restrict__ W,
                             const float* __restrict__ bias,
                             const float* __restrict__ Call,
                             const float* __restrict__ COS,
                             float* __restrict__ cOut,
                             _Float16* __restrict__ uOut) {
    int b = blockIdx.x;
    int t = threadIdx.x;          // 0..255
    int d = t & 127;
    int h = t >> 7;               // 0/1
    __shared__ int sE[KN], sR[KN], sT[KN];
    __shared__ float sAgg[2][3][DIM];
    __shared__ float sAcc[2][DIM];
    __shared__ float sQ[DIM];
    __shared__ float sU[2][DIM];
    __shared__ float sRed[DIM];

    if (t < KN) {
        sE[t] = ngh_node[b * KN + t];
        sR[t] = ngh_eidx[b * KN + t];
        sT[t] = ngh_ts[b * KN + t] - ts[b] + 364;
    }
    __syncthreads();

    float aN = 0.f, aC = 0.f, aR = 0.f;
    int k0 = h * 16;
    for (int k = k0; k < k0 + 16; ++k) {
        int e = sE[k];
        if (e < 0) continue;
        aN += symbol_emb[(size_t)e * DIM + d];
        aC += COS[sT[k] * DIM + d];
        aR += symbol_emb[(size_t)(NUM_ENT + sR[k]) * DIM + d];
    }
    sAgg[h][0][d] = aN; sAgg[h][1][d] = aC; sAgg[h][2][d] = aR;

    int cnt = 0;
    #pragma unroll
    for (int k = 0; k < KN; ++k) cnt += (sE[k] >= 0) ? 1 : 0;
    __syncthreads();

    if (h == 0) {
        sAgg[0][0][d] += sAgg[1][0][d];
        sAgg[0][1][d] += sAgg[1][1][d];
        sAgg[0][2][d] += sAgg[1][2][d];
    }
    __syncthreads();

    int j0 = h * 64;
    float acc = 0.f;
    #pragma unroll 8
    for (int j = 0; j < 64; ++j) acc += sAgg[0][0][j0 + j] * W[(j0 + j) * DIM + d];
    #pragma unroll 8
    for (int j = 0; j < 64; ++j) acc += sAgg[0][1][j0 + j] * W[(128 + j0 + j) * DIM + d];
    #pragma unroll 8
    for (int j = 0; j < 64; ++j) acc += sAgg[0][2][j0 + j] * W[(256 + j0 + j) * DIM + d];
    sAcc[h][d] = acc;
    __syncthreads();

    if (h == 0) {
        float total = sAcc[0][d] + sAcc[1][d] + (float)cnt * bias[d];
        float denom = (float)(cnt > 0 ? cnt : 1);
        float sub = tanhf(total / denom);
        float q = sub * symbol_emb[(size_t)(NUM_ENT + rel_idx[b]) * DIM + d];
        sQ[d] = q;
    }
    __syncthreads();

    float u = 0.f;
    #pragma unroll 8
    for (int dd = 0; dd < 64; ++dd) u += sQ[j0 + dd] * proj_w[(j0 + dd) * 256 + d];
    sU[h][d] = u;
    __syncthreads();
    if (h == 0) uOut[b * DIM + d] = (_Float16)(sU[0][d] + sU[1][d]);

    if (h == 0) sRed[d] = sQ[d] * Call[d];
    __syncthreads();
    for (int s = 64; s > 0; s >>= 1) {
        if (t < s) sRed[t] += sRed[t + s];
        __syncthreads();
    }
    if (t == 0) cOut[b] = sRed[0];
}

// ---------------- Kernel D: score^T = S-tile(regs) x U, LDS-transposed stores --
// Fragment pinning + MFMA identical to round-5 (passed). NEW (one mechanism):
// per qg the 16x256 result is staged in LDS and stored as FULL-ROW bursts --
// each store instruction = 64 lanes x 16B = 1KB contiguous in ONE output row
// (the fill-kernel pattern that hits 6.8 TB/s), nontemporal (write-once stream,
// no L2 allocate; row edges are 64B-aligned = HBM sector granularity).
__global__ __launch_bounds__(256) void score_kernel(const _Float16* __restrict__ U,
                                                    const float* __restrict__ S,
                                                    const float* __restrict__ cArr,
                                                    float* __restrict__ out) {
    __shared__ float xp[16 * LDSW];   // 16 q-rows x 264 words = 16896 B
    int wgid = blockIdx.x;
    int swz = (wgid & 7) * 392 + (wgid >> 3);   // bijective, 3136 = 8*392
    int xtile = swz >> 4;          // 0..195
    int qchunk = swz & 15;         // 0..15
    int n0 = xtile * NTILE;

    int lane = threadIdx.x & 63;
    int wave = threadIdx.x >> 6;
    int lr = lane & 15;
    int lg = lane >> 4;            // 0..3
    int lk = lg * 8;               // k offset within 32

    // wave pins rows [n0 + wave*64, +64): 16 x f16x8 fragments (f32->f16)
    f16x8 a[4][4];
    #pragma unroll
    for (int nn = 0; nn < 4; ++nn) {
        const float* sp = S + (size_t)(n0 + wave * 64 + nn * 16 + lr) * DIM + lk;
        #pragma unroll
        for (int kk = 0; kk < 4; ++kk) {
            float4 v0 = *reinterpret_cast<const float4*>(sp + kk * 32);
            float4 v1 = *reinterpret_cast<const float4*>(sp + kk * 32 + 4);
            f16x8 af;
            af[0] = (_Float16)v0.x; af[1] = (_Float16)v0.y;
            af[2] = (_Float16)v0.z; af[3] = (_Float16)v0.w;
            af[4] = (_Float16)v1.x; af[5] = (_Float16)v1.y;
            af[6] = (_Float16)v1.z; af[7] = (_Float16)v1.w;
            a[nn][kk] = af;
        }
    }

    int qbase = qchunk * 64;
    #pragma unroll
    for (int qg = 0; qg < 4; ++qg) {
        int q0 = qbase + qg * 16;
        f16x8 bfr[4];
        #pragma unroll
        for (int kk = 0; kk < 4; ++kk)
            bfr[kk] = *reinterpret_cast<const f16x8*>(U + (q0 + lr) * DIM + kk * 32 + lk);
        float cv = cArr[q0 + lr];

        f32x4 acc[4];
        #pragma unroll
        for (int nn = 0; nn < 4; ++nn) acc[nn] = (f32x4){0.f, 0.f, 0.f, 0.f};

        #pragma unroll
        for (int kk = 0; kk < 4; ++kk)
            #pragma unroll
            for (int nn = 0; nn < 4; ++nn)
                acc[nn] = __builtin_amdgcn_mfma_f32_16x16x32_f16(a[nn][kk], bfr[kk], acc[nn], 0, 0, 0);

        // stage (score + c) into LDS: row = q-local (lr), col = entity-local
        #pragma unroll
        for (int nn = 0; nn < 4; ++nn) {
            f32x4 v = acc[nn] + cv;
            *reinterpret_cast<f32x4*>(&xp[lr * LDSW + wave * 64 + nn * 16 + lg * 4]) = v;
        }
        __syncthreads();

        // full-row stores: wave w -> q-local rows 4w..4w+3, 1KB contiguous each
        #pragma unroll
        for (int j = 0; j < 4; ++j) {
            int row = wave * 4 + j;
            int q = q0 + row;
            int e = n0 + lane * 4;
            if (e < NUM_ENT) {
                f32x4 v = *reinterpret_cast<const f32x4*>(&xp[row * LDSW + lane * 4]);
                __builtin_nontemporal_store(
                    v, reinterpret_cast<f32x4*>(out + (size_t)q * NUM_ENT + e));
            }
        }
        __syncthreads();
    }
}

extern "C" void kernel_launch(void* const* d_in, const int* in_sizes, int n_in,
                              void* d_out, int out_size, void* d_ws, size_t ws_size,
                              hipStream_t stream) {
    const int*   rel_idx    = (const int*)d_in[1];
    const int*   ts         = (const int*)d_in[2];
    const int*   ngh_node   = (const int*)d_in[3];
    const int*   ngh_eidx   = (const int*)d_in[4];
    const int*   ngh_ts     = (const int*)d_in[5];
    const float* symbol_emb = (const float*)d_in[6];
    const float* gcn_w_w    = (const float*)d_in[7];
    const float* gcn_w_b    = (const float*)d_in[8];
    const float* proj_w     = (const float*)d_in[9];
    const float* proj_b     = (const float*)d_in[10];
    const float* basis_freq = (const float*)d_in[11];
    const float* phase      = (const float*)d_in[12];
    float* out = (float*)d_out;

    char* ws = (char*)d_ws;
    float*     W    = (float*)(ws + 0);          // 384*128*4 = 196608
    float*     bias = (float*)(ws + 196608);     // 512
    float*     Call = (float*)(ws + 197120);     // 512
    float*     COS  = (float*)(ws + 197632);     // 729*128*4 = 373248
    float*     cArr = (float*)(ws + 570880);     // 1024*4 = 4096
    _Float16*  U    = (_Float16*)(ws + 574976);  // 1024*128*2 = 262144

    prep_kernel<<<385 + TBL, 128, 0, stream>>>(gcn_w_w, gcn_w_b, proj_w, proj_b,
                                               phase, basis_freq, W, bias, Call, COS);
    query_kernel<<<BQ, 256, 0, stream>>>(rel_idx, ts, ngh_node, ngh_eidx, ngh_ts,
                                         symbol_emb, proj_w, W, bias, Call, COS,
                                         cArr, U);
    score_kernel<<<NXT * 16, 256, 0, stream>>>(U, symbol_emb, cArr, out);
}

// Round 7
// 124.659 us; speedup vs baseline: 1.1381x; 1.0373x over previous
//
#include <hip/hip_runtime.h>
#include <hip/hip_bf16.h>

#define NUM_ENT 50000
#define NUM_REL 500
#define DIM 128
#define BQ 1024
#define KN 32
#define TBL 729          // dt in [-364, 364]
#define NTILE 256        // entities per score block
#define NXT 196          // 196*256 = 50176 >= 50000; max row 50175 < 50501 in-bounds
#define LDSW 264         // padded words per q-row in LDS transpose buffer

typedef _Float16 f16x8 __attribute__((ext_vector_type(8)));
typedef float f32x4 __attribute__((ext_vector_type(4)));

// ---------------- Kernel A: fold weights + cos table (verbatim r3/r6, proven) --
__global__ void prep_kernel(const float* __restrict__ gcn_w_w,
                            const float* __restrict__ gcn_w_b,
                            const float* __restrict__ proj_w,
                            const float* __restrict__ proj_b,
                            const float* __restrict__ phase,
                            const float* __restrict__ basis_freq,
                            float* __restrict__ W,
                            float* __restrict__ bias,
                            float* __restrict__ Call,
                            float* __restrict__ COS) {
    int j = blockIdx.x;
    int d = threadIdx.x;
    if (j < 256) {
        float acc = 0.f;
        for (int f = 0; f < DIM; ++f)
            acc += gcn_w_w[d * 256 + f] * proj_w[f * 256 + j];
        W[j * DIM + d] = acc;
    } else if (j < 384) {
        W[j * DIM + d] = gcn_w_w[d * 256 + 128 + (j - 256)];
    } else if (j == 384) {
        float b1 = 0.f;
        for (int f = 0; f < DIM; ++f) b1 += proj_b[f] * gcn_w_w[d * 256 + f];
        bias[d] = b1 + gcn_w_b[d];
        float cc = 0.f;
        for (int g = 0; g < DIM; ++g) cc += cosf(phase[g]) * proj_w[d * 256 + 128 + g];
        Call[d] = cc + proj_b[d];
    } else {
        int row = j - 385;                 // 0..728
        COS[row * DIM + d] = cosf((float)(row - 364) * basis_freq[d] + phase[d]);
    }
}

// ---------------- Kernel C: per-query pipeline (NEW: vectorized gathers) -------
// 256 threads: (g = t>>5, c = t&31). All 96 gathered rows (32 node, 32 cos,
// 32 rel) loaded as independent float4s, fully unrolled, branchless select;
// partials reduced once through LDS. Dot phases keep the proven r3 h-split.
__global__ __launch_bounds__(256) void query_kernel(const int* __restrict__ rel_idx,
                             const int* __restrict__ ts,
                             const int* __restrict__ ngh_node,
                             const int* __restrict__ ngh_eidx,
                             const int* __restrict__ ngh_ts,
                             const float* __restrict__ symbol_emb,
                             const float* __restrict__ proj_w,
                             const float* __restrict__ W,
                             const float* __restrict__ bias,
                             const float* __restrict__ Call,
                             const float* __restrict__ COS,
                             float* __restrict__ cOut,
                             _Float16* __restrict__ uOut) {
    int b = blockIdx.x;
    int t = threadIdx.x;          // 0..255
    __shared__ int sE[KN], sR[KN], sT[KN];
    __shared__ float sP[3][8][DIM];     // 12 KB partials
    __shared__ float sAgg[3 * DIM];
    __shared__ float sAcc[2][DIM];
    __shared__ float sQ[DIM];
    __shared__ float sU[2][DIM];
    __shared__ float sC[2];

    if (t < KN) {
        sE[t] = ngh_node[b * KN + t];
        sR[t] = ngh_eidx[b * KN + t];
        int dt = ngh_ts[b * KN + t] - ts[b] + 364;
        sT[t] = dt < 0 ? 0 : (dt > 728 ? 728 : dt);
    }
    __syncthreads();   // B1

    int c = t & 31;
    int g = t >> 5;    // 0..7
    f32x4 pN = {0.f,0.f,0.f,0.f}, pC = pN, pR = pN;
    #pragma unroll
    for (int i = 0; i < 4; ++i) {
        int k = i * 8 + g;
        int e = sE[k];
        bool valid = (e >= 0);
        int es = valid ? e : 0;
        f32x4 vN = *reinterpret_cast<const f32x4*>(symbol_emb + (size_t)es * DIM + c * 4);
        f32x4 vC = *reinterpret_cast<const f32x4*>(COS + sT[k] * DIM + c * 4);
        f32x4 vR = *reinterpret_cast<const f32x4*>(symbol_emb + (size_t)(NUM_ENT + sR[k]) * DIM + c * 4);
        if (valid) { pN += vN; pC += vC; pR += vR; }
    }
    *reinterpret_cast<f32x4*>(&sP[0][g][c * 4]) = pN;
    *reinterpret_cast<f32x4*>(&sP[1][g][c * 4]) = pC;
    *reinterpret_cast<f32x4*>(&sP[2][g][c * 4]) = pR;

    int cnt = 0;
    #pragma unroll
    for (int k = 0; k < KN; ++k) cnt += (sE[k] >= 0) ? 1 : 0;
    __syncthreads();   // B2

    #pragma unroll
    for (int o = t; o < 384; o += 256) {
        float s = 0.f;
        #pragma unroll
        for (int gg = 0; gg < 8; ++gg) s += sP[o >> 7][gg][o & 127];
        sAgg[o] = s;
    }
    __syncthreads();   // B3

    int d = t & 127;
    int h = t >> 7;
    int j0 = h * 64;
    float acc = 0.f;
    #pragma unroll 8
    for (int j = 0; j < 64; ++j) acc += sAgg[j0 + j] * W[(j0 + j) * DIM + d];
    #pragma unroll 8
    for (int j = 0; j < 64; ++j) acc += sAgg[128 + j0 + j] * W[(128 + j0 + j) * DIM + d];
    #pragma unroll 8
    for (int j = 0; j < 64; ++j) acc += sAgg[256 + j0 + j] * W[(256 + j0 + j) * DIM + d];
    sAcc[h][d] = acc;
    __syncthreads();   // B4

    if (h == 0) {
        float total = sAcc[0][d] + sAcc[1][d] + (float)cnt * bias[d];
        float denom = (float)(cnt > 0 ? cnt : 1);
        float sub = tanhf(total / denom);
        sQ[d] = sub * symbol_emb[(size_t)(NUM_ENT + rel_idx[b]) * DIM + d];
    }
    __syncthreads();   // B5

    float u = 0.f;
    #pragma unroll 8
    for (int dd = 0; dd < 64; ++dd) u += sQ[j0 + dd] * proj_w[(j0 + dd) * 256 + d];
    sU[h][d] = u;

    float cp = (t < 128) ? sQ[t] * Call[t] : 0.f;
    #pragma unroll
    for (int m = 1; m < 64; m <<= 1) cp += __shfl_xor(cp, m, 64);
    if (t == 0) sC[0] = cp;
    if (t == 64) sC[1] = cp;
    __syncthreads();   // B6

    if (h == 0) uOut[b * DIM + d] = (_Float16)(sU[0][d] + sU[1][d]);
    if (t == 0) cOut[b] = sC[0] + sC[1];
}

// ---------------- Kernel D: score (VERBATIM r6, passed) ----------------
__global__ __launch_bounds__(256) void score_kernel(const _Float16* __restrict__ U,
                                                    const float* __restrict__ S,
                                                    const float* __restrict__ cArr,
                                                    float* __restrict__ out) {
    __shared__ float xp[16 * LDSW];   // 16 q-rows x 264 words = 16896 B
    int wgid = blockIdx.x;
    int swz = (wgid & 7) * 392 + (wgid >> 3);   // bijective, 3136 = 8*392
    int xtile = swz >> 4;          // 0..195
    int qchunk = swz & 15;         // 0..15
    int n0 = xtile * NTILE;

    int lane = threadIdx.x & 63;
    int wave = threadIdx.x >> 6;
    int lr = lane & 15;
    int lg = lane >> 4;            // 0..3
    int lk = lg * 8;               // k offset within 32

    f16x8 a[4][4];
    #pragma unroll
    for (int nn = 0; nn < 4; ++nn) {
        const float* sp = S + (size_t)(n0 + wave * 64 + nn * 16 + lr) * DIM + lk;
        #pragma unroll
        for (int kk = 0; kk < 4; ++kk) {
            float4 v0 = *reinterpret_cast<const float4*>(sp + kk * 32);
            float4 v1 = *reinterpret_cast<const float4*>(sp + kk * 32 + 4);
            f16x8 af;
            af[0] = (_Float16)v0.x; af[1] = (_Float16)v0.y;
            af[2] = (_Float16)v0.z; af[3] = (_Float16)v0.w;
            af[4] = (_Float16)v1.x; af[5] = (_Float16)v1.y;
            af[6] = (_Float16)v1.z; af[7] = (_Float16)v1.w;
            a[nn][kk] = af;
        }
    }

    int qbase = qchunk * 64;
    #pragma unroll
    for (int qg = 0; qg < 4; ++qg) {
        int q0 = qbase + qg * 16;
        f16x8 bfr[4];
        #pragma unroll
        for (int kk = 0; kk < 4; ++kk)
            bfr[kk] = *reinterpret_cast<const f16x8*>(U + (q0 + lr) * DIM + kk * 32 + lk);
        float cv = cArr[q0 + lr];

        f32x4 acc[4];
        #pragma unroll
        for (int nn = 0; nn < 4; ++nn) acc[nn] = (f32x4){0.f, 0.f, 0.f, 0.f};

        #pragma unroll
        for (int kk = 0; kk < 4; ++kk)
            #pragma unroll
            for (int nn = 0; nn < 4; ++nn)
                acc[nn] = __builtin_amdgcn_mfma_f32_16x16x32_f16(a[nn][kk], bfr[kk], acc[nn], 0, 0, 0);

        #pragma unroll
        for (int nn = 0; nn < 4; ++nn) {
            f32x4 v = acc[nn] + cv;
            *reinterpret_cast<f32x4*>(&xp[lr * LDSW + wave * 64 + nn * 16 + lg * 4]) = v;
        }
        __syncthreads();

        #pragma unroll
        for (int j = 0; j < 4; ++j) {
            int row = wave * 4 + j;
            int q = q0 + row;
            int e = n0 + lane * 4;
            if (e < NUM_ENT) {
                f32x4 v = *reinterpret_cast<const f32x4*>(&xp[row * LDSW + lane * 4]);
                __builtin_nontemporal_store(
                    v, reinterpret_cast<f32x4*>(out + (size_t)q * NUM_ENT + e));
            }
        }
        __syncthreads();
    }
}

extern "C" void kernel_launch(void* const* d_in, const int* in_sizes, int n_in,
                              void* d_out, int out_size, void* d_ws, size_t ws_size,
                              hipStream_t stream) {
    const int*   rel_idx    = (const int*)d_in[1];
    const int*   ts         = (const int*)d_in[2];
    const int*   ngh_node   = (const int*)d_in[3];
    const int*   ngh_eidx   = (const int*)d_in[4];
    const int*   ngh_ts     = (const int*)d_in[5];
    const float* symbol_emb = (const float*)d_in[6];
    const float* gcn_w_w    = (const float*)d_in[7];
    const float* gcn_w_b    = (const float*)d_in[8];
    const float* proj_w     = (const float*)d_in[9];
    const float* proj_b     = (const float*)d_in[10];
    const float* basis_freq = (const float*)d_in[11];
    const float* phase      = (const float*)d_in[12];
    float* out = (float*)d_out;

    char* ws = (char*)d_ws;
    float*     W    = (float*)(ws + 0);          // 384*128*4 = 196608
    float*     bias = (float*)(ws + 196608);     // 512
    float*     Call = (float*)(ws + 197120);     // 512
    float*     COS  = (float*)(ws + 197632);     // 729*128*4 = 373248
    float*     cArr = (float*)(ws + 570880);     // 1024*4 = 4096
    _Float16*  U    = (_Float16*)(ws + 574976);  // 1024*128*2 = 262144

    prep_kernel<<<385 + TBL, 128, 0, stream>>>(gcn_w_w, gcn_w_b, proj_w, proj_b,
                                               phase, basis_freq, W, bias, Call, COS);
    query_kernel<<<BQ, 256, 0, stream>>>(rel_idx, ts, ngh_node, ngh_eidx, ngh_ts,
                                         symbol_emb, proj_w, W, bias, Call, COS,
                                         cArr, U);
    score_kernel<<<NXT * 16, 256, 0, stream>>>(U, symbol_emb, cArr, out);
}

// Round 8
// 105.751 us; speedup vs baseline: 1.3416x; 1.1788x over previous
//
#include <hip/hip_runtime.h>
#include <hip/hip_bf16.h>

#define NUM_ENT 50000
#define NUM_REL 500
#define DIM 128
#define BQ 1024
#define KN 32
#define TBL 729          // dt in [-364, 364]
#define NTILE 256        // entities per score block
#define NXT 196          // 196*256 = 50176 >= 50000; max row 50175 < 50501 in-bounds
#define LDSW 264         // padded words per q-row in LDS transpose buffer

typedef _Float16 f16x8 __attribute__((ext_vector_type(8)));
typedef _Float16 f16x4 __attribute__((ext_vector_type(4)));
typedef float f32x4 __attribute__((ext_vector_type(4)));

// ---------------- Kernel A: fold weights + cos table (verbatim r3/r6/r7) -------
__global__ void prep_kernel(const float* __restrict__ gcn_w_w,
                            const float* __restrict__ gcn_w_b,
                            const float* __restrict__ proj_w,
                            const float* __restrict__ proj_b,
                            const float* __restrict__ phase,
                            const float* __restrict__ basis_freq,
                            float* __restrict__ W,
                            float* __restrict__ bias,
                            float* __restrict__ Call,
                            float* __restrict__ COS) {
    int j = blockIdx.x;
    int d = threadIdx.x;
    if (j < 256) {
        float acc = 0.f;
        for (int f = 0; f < DIM; ++f)
            acc += gcn_w_w[d * 256 + f] * proj_w[f * 256 + j];
        W[j * DIM + d] = acc;
    } else if (j < 384) {
        W[j * DIM + d] = gcn_w_w[d * 256 + 128 + (j - 256)];
    } else if (j == 384) {
        float b1 = 0.f;
        for (int f = 0; f < DIM; ++f) b1 += proj_b[f] * gcn_w_w[d * 256 + f];
        bias[d] = b1 + gcn_w_b[d];
        float cc = 0.f;
        for (int g = 0; g < DIM; ++g) cc += cosf(phase[g]) * proj_w[d * 256 + 128 + g];
        Call[d] = cc + proj_b[d];
    } else {
        int row = j - 385;                 // 0..728
        COS[row * DIM + d] = cosf((float)(row - 364) * basis_freq[d] + phase[d]);
    }
}

// ---------------- Kernel C: per-query pipeline (verbatim r7, passed) -----------
__global__ __launch_bounds__(256) void query_kernel(const int* __restrict__ rel_idx,
                             const int* __restrict__ ts,
                             const int* __restrict__ ngh_node,
                             const int* __restrict__ ngh_eidx,
                             const int* __restrict__ ngh_ts,
                             const float* __restrict__ symbol_emb,
                             const float* __restrict__ proj_w,
                             const float* __restrict__ W,
                             const float* __restrict__ bias,
                             const float* __restrict__ Call,
                             const float* __restrict__ COS,
                             float* __restrict__ cOut,
                             _Float16* __restrict__ uOut) {
    int b = blockIdx.x;
    int t = threadIdx.x;          // 0..255
    __shared__ int sE[KN], sR[KN], sT[KN];
    __shared__ float sP[3][8][DIM];     // 12 KB partials
    __shared__ float sAgg[3 * DIM];
    __shared__ float sAcc[2][DIM];
    __shared__ float sQ[DIM];
    __shared__ float sU[2][DIM];
    __shared__ float sC[2];

    if (t < KN) {
        sE[t] = ngh_node[b * KN + t];
        sR[t] = ngh_eidx[b * KN + t];
        int dt = ngh_ts[b * KN + t] - ts[b] + 364;
        sT[t] = dt < 0 ? 0 : (dt > 728 ? 728 : dt);
    }
    __syncthreads();   // B1

    int c = t & 31;
    int g = t >> 5;    // 0..7
    f32x4 pN = {0.f,0.f,0.f,0.f}, pC = pN, pR = pN;
    #pragma unroll
    for (int i = 0; i < 4; ++i) {
        int k = i * 8 + g;
        int e = sE[k];
        bool valid = (e >= 0);
        int es = valid ? e : 0;
        f32x4 vN = *reinterpret_cast<const f32x4*>(symbol_emb + (size_t)es * DIM + c * 4);
        f32x4 vC = *reinterpret_cast<const f32x4*>(COS + sT[k] * DIM + c * 4);
        f32x4 vR = *reinterpret_cast<const f32x4*>(symbol_emb + (size_t)(NUM_ENT + sR[k]) * DIM + c * 4);
        if (valid) { pN += vN; pC += vC; pR += vR; }
    }
    *reinterpret_cast<f32x4*>(&sP[0][g][c * 4]) = pN;
    *reinterpret_cast<f32x4*>(&sP[1][g][c * 4]) = pC;
    *reinterpret_cast<f32x4*>(&sP[2][g][c * 4]) = pR;

    int cnt = 0;
    #pragma unroll
    for (int k = 0; k < KN; ++k) cnt += (sE[k] >= 0) ? 1 : 0;
    __syncthreads();   // B2

    #pragma unroll
    for (int o = t; o < 384; o += 256) {
        float s = 0.f;
        #pragma unroll
        for (int gg = 0; gg < 8; ++gg) s += sP[o >> 7][gg][o & 127];
        sAgg[o] = s;
    }
    __syncthreads();   // B3

    int d = t & 127;
    int h = t >> 7;
    int j0 = h * 64;
    float acc = 0.f;
    #pragma unroll 8
    for (int j = 0; j < 64; ++j) acc += sAgg[j0 + j] * W[(j0 + j) * DIM + d];
    #pragma unroll 8
    for (int j = 0; j < 64; ++j) acc += sAgg[128 + j0 + j] * W[(128 + j0 + j) * DIM + d];
    #pragma unroll 8
    for (int j = 0; j < 64; ++j) acc += sAgg[256 + j0 + j] * W[(256 + j0 + j) * DIM + d];
    sAcc[h][d] = acc;
    __syncthreads();   // B4

    if (h == 0) {
        float total = sAcc[0][d] + sAcc[1][d] + (float)cnt * bias[d];
        float denom = (float)(cnt > 0 ? cnt : 1);
        float sub = tanhf(total / denom);
        sQ[d] = sub * symbol_emb[(size_t)(NUM_ENT + rel_idx[b]) * DIM + d];
    }
    __syncthreads();   // B5

    float u = 0.f;
    #pragma unroll 8
    for (int dd = 0; dd < 64; ++dd) u += sQ[j0 + dd] * proj_w[(j0 + dd) * 256 + d];
    sU[h][d] = u;

    float cp = (t < 128) ? sQ[t] * Call[t] : 0.f;
    #pragma unroll
    for (int m = 1; m < 64; m <<= 1) cp += __shfl_xor(cp, m, 64);
    if (t == 0) sC[0] = cp;
    if (t == 64) sC[1] = cp;
    __syncthreads();   // B6

    if (h == 0) uOut[b * DIM + d] = (_Float16)(sU[0][d] + sU[1][d]);
    if (t == 0) cOut[b] = sC[0] + sC[1];
}

// ---------------- Kernel D: score with COALESCED LDS-staged A-tile ----------------
// ONE mechanism vs r6/r7: the 256x128 f32 tile is staged with fully-coalesced
// 1KB-per-instruction loads into f16 XOR-swizzled LDS (corrected r4: i<32 stages
// ALL 8192 float4s; r4 staged only 1/4 -> NaN), frags then read from LDS
// (swizzle makes the 16-way read conflict 2-way = free). The 64KB buffer is
// REUSED as the store-transpose xp after frags are pinned (extra barrier).
// Epilogue/stores/swizzle/grid byte-identical to r6/r7.
__global__ __launch_bounds__(256) void score_kernel(const _Float16* __restrict__ U,
                                                    const float* __restrict__ S,
                                                    const float* __restrict__ cArr,
                                                    float* __restrict__ out) {
    __shared__ char smem[65536];               // f16 tile, then reused as xp
    float* xp = reinterpret_cast<float*>(smem);

    int wgid = blockIdx.x;
    int swz = (wgid & 7) * 392 + (wgid >> 3);   // bijective, 3136 = 8*392
    int xtile = swz >> 4;          // 0..195
    int qchunk = swz & 15;         // 0..15
    int n0 = xtile * NTILE;

    int t = threadIdx.x;
    int lane = t & 63;
    int wave = t >> 6;
    int lr = lane & 15;
    int lg = lane >> 4;            // 0..3
    int lk = lg * 8;               // k offset within 32

    // --- coalesced staging: 8192 float4 = full 256x128 f32 tile ---
    const float* src = S + (size_t)n0 * DIM;
    #pragma unroll 8
    for (int i = 0; i < 32; ++i) {
        int fi = i * 256 + t;                  // 0..8191
        float4 v = *reinterpret_cast<const float4*>(src + (size_t)fi * 4);
        int r = fi >> 5;                       // row 0..255
        int k8 = (fi & 31) * 8;                // byte col 0..248
        f16x4 o;
        o[0] = (_Float16)v.x; o[1] = (_Float16)v.y;
        o[2] = (_Float16)v.z; o[3] = (_Float16)v.w;
        int byte = r * 256 + k8;
        byte ^= (r & 7) << 4;                  // XOR swizzle (write side)
        *reinterpret_cast<f16x4*>(smem + byte) = o;
    }
    __syncthreads();

    // --- pin fragments from swizzled LDS ---
    f16x8 a[4][4];
    #pragma unroll
    for (int nn = 0; nn < 4; ++nn) {
        int r = wave * 64 + nn * 16 + lr;
        int rowbase = r * 256;
        int sw = (r & 7) << 4;
        #pragma unroll
        for (int kk = 0; kk < 4; ++kk) {
            int byte = (rowbase + (kk * 32 + lk) * 2) ^ sw;
            a[nn][kk] = *reinterpret_cast<const f16x8*>(smem + byte);
        }
    }
    __syncthreads();   // all tile reads done before xp overwrites the buffer

    int qbase = qchunk * 64;
    #pragma unroll
    for (int qg = 0; qg < 4; ++qg) {
        int q0 = qbase + qg * 16;
        f16x8 bfr[4];
        #pragma unroll
        for (int kk = 0; kk < 4; ++kk)
            bfr[kk] = *reinterpret_cast<const f16x8*>(U + (q0 + lr) * DIM + kk * 32 + lk);
        float cv = cArr[q0 + lr];

        f32x4 acc[4];
        #pragma unroll
        for (int nn = 0; nn < 4; ++nn) acc[nn] = (f32x4){0.f, 0.f, 0.f, 0.f};

        #pragma unroll
        for (int kk = 0; kk < 4; ++kk)
            #pragma unroll
            for (int nn = 0; nn < 4; ++nn)
                acc[nn] = __builtin_amdgcn_mfma_f32_16x16x32_f16(a[nn][kk], bfr[kk], acc[nn], 0, 0, 0);

        #pragma unroll
        for (int nn = 0; nn < 4; ++nn) {
            f32x4 v = acc[nn] + cv;
            *reinterpret_cast<f32x4*>(&xp[lr * LDSW + wave * 64 + nn * 16 + lg * 4]) = v;
        }
        __syncthreads();

        #pragma unroll
        for (int j = 0; j < 4; ++j) {
            int row = wave * 4 + j;
            int q = q0 + row;
            int e = n0 + lane * 4;
            if (e < NUM_ENT) {
                f32x4 v = *reinterpret_cast<const f32x4*>(&xp[row * LDSW + lane * 4]);
                __builtin_nontemporal_store(
                    v, reinterpret_cast<f32x4*>(out + (size_t)q * NUM_ENT + e));
            }
        }
        __syncthreads();
    }
}

extern "C" void kernel_launch(void* const* d_in, const int* in_sizes, int n_in,
                              void* d_out, int out_size, void* d_ws, size_t ws_size,
                              hipStream_t stream) {
    const int*   rel_idx    = (const int*)d_in[1];
    const int*   ts         = (const int*)d_in[2];
    const int*   ngh_node   = (const int*)d_in[3];
    const int*   ngh_eidx   = (const int*)d_in[4];
    const int*   ngh_ts     = (const int*)d_in[5];
    const float* symbol_emb = (const float*)d_in[6];
    const float* gcn_w_w    = (const float*)d_in[7];
    const float* gcn_w_b    = (const float*)d_in[8];
    const float* proj_w     = (const float*)d_in[9];
    const float* proj_b     = (const float*)d_in[10];
    const float* basis_freq = (const float*)d_in[11];
    const float* phase      = (const float*)d_in[12];
    float* out = (float*)d_out;

    char* ws = (char*)d_ws;
    float*     W    = (float*)(ws + 0);          // 384*128*4 = 196608
    float*     bias = (float*)(ws + 196608);     // 512
    float*     Call = (float*)(ws + 197120);     // 512
    float*     COS  = (float*)(ws + 197632);     // 729*128*4 = 373248
    float*     cArr = (float*)(ws + 570880);     // 1024*4 = 4096
    _Float16*  U    = (_Float16*)(ws + 574976);  // 1024*128*2 = 262144

    prep_kernel<<<385 + TBL, 128, 0, stream>>>(gcn_w_w, gcn_w_b, proj_w, proj_b,
                                               phase, basis_freq, W, bias, Call, COS);
    query_kernel<<<BQ, 256, 0, stream>>>(rel_idx, ts, ngh_node, ngh_eidx, ngh_ts,
                                         symbol_emb, proj_w, W, bias, Call, COS,
                                         cArr, U);
    score_kernel<<<NXT * 16, 256, 0, stream>>>(U, symbol_emb, cArr, out);
}